// Round 13
// baseline (907.789 us; speedup 1.0000x reference)
//
#include <hip/hip_runtime.h>
#include <math.h>

// ---------------------------------------------------------------------------
// PGCN twin-branch GCN. fp32. R13 = R12 + two-node interleaved gathers
// (2 independent chains per 32-lane group -> 2x outstanding loads on the
// latency-bound gather block). Per-node FMA order unchanged (absmax 0).
// ---------------------------------------------------------------------------

#define TPB 256

__device__ __forceinline__ int swz_block(int bid, int nb) {
  return (bid & 7) * (nb >> 3) + (bid >> 3);
}

__device__ __forceinline__ void f4fma(float4& a, const float4 b, float s) {
  a.x += b.x * s; a.y += b.y * s; a.z += b.z * s; a.w += b.w * s;
}
__device__ __forceinline__ float4 f4s(const float4 a, float s) {
  return make_float4(a.x * s, a.y * s, a.z * s, a.w * s);
}

// ---------------- merged CSR build (both branches, concatenated) ------------
__global__ __launch_bounds__(TPB) void count2_k(const int* __restrict__ ec0,
                                                const int* __restrict__ ec1,
                                                int* __restrict__ cnt, int N,
                                                int E) {
  int e = blockIdx.x * TPB + threadIdx.x;
  if (e < 2 * E) {
    int br = e >= E;
    int el = e - br * E;
    int c = (br ? ec1[el] : ec0[el]) + br * N;
    atomicAdd(&cnt[c], 1);
  }
}

__global__ __launch_bounds__(512) void scan1_k(const int* __restrict__ cnt,
                                               int* __restrict__ rowptr,
                                               int* __restrict__ bsum, int tn) {
  __shared__ int s[512];
  int tid = threadIdx.x;
  int gid = blockIdx.x * 512 + tid;
  int v = (gid < tn) ? cnt[gid] : 0;
  s[tid] = v;
  __syncthreads();
  for (int o = 1; o < 512; o <<= 1) {
    int t = (tid >= o) ? s[tid - o] : 0;
    __syncthreads();
    s[tid] += t;
    __syncthreads();
  }
  if (gid < tn) rowptr[gid] = s[tid] - v;
  if (tid == 511) bsum[blockIdx.x] = s[511];
}

__global__ __launch_bounds__(TPB) void scan2_k(int* __restrict__ bsum, int nb) {
  __shared__ int s[TPB];
  int tid = threadIdx.x;
  int v = (tid < nb) ? bsum[tid] : 0;
  s[tid] = v;
  __syncthreads();
  for (int o = 1; o < TPB; o <<= 1) {
    int t = (tid >= o) ? s[tid - o] : 0;
    __syncthreads();
    s[tid] += t;
    __syncthreads();
  }
  if (tid < nb) bsum[tid] = s[tid] - v;
}

__global__ __launch_bounds__(512) void scan3_k(int* __restrict__ rowptr,
                                               const int* __restrict__ bsum,
                                               int tn, int tE) {
  int gid = blockIdx.x * 512 + threadIdx.x;
  if (gid < tn) rowptr[gid] += bsum[blockIdx.x];
  if (gid == 0) rowptr[tn] = tE;
}

__global__ __launch_bounds__(TPB) void fill2_k(const int* __restrict__ ec0,
                                               const int* __restrict__ ec1,
                                               const int* __restrict__ rowptr,
                                               int* __restrict__ fil,
                                               int* __restrict__ csr, int N,
                                               int E) {
  int e = blockIdx.x * TPB + threadIdx.x;
  if (e < 2 * E) {
    int br = e >= E;
    int el = e - br * E;
    int c = (br ? ec1[el] : ec0[el]) + br * N;
    int p = rowptr[c] + atomicAdd(&fil[c], 1);
    csr[p] = e;
  }
}

__global__ __launch_bounds__(TPB) void sortadj_k(const int* __restrict__ rowptr,
                                                 int* __restrict__ csr, int tn) {
  int i = blockIdx.x * TPB + threadIdx.x;
  if (i >= tn) return;
  int s = rowptr[i], e = rowptr[i + 1];
  for (int a = s + 1; a < e; ++a) {
    int v = csr[a];
    int b = a - 1;
    while (b >= s && csr[b] > v) { csr[b + 1] = csr[b]; --b; }
    csr[b + 1] = v;
  }
}

__global__ __launch_bounds__(TPB) void deg2_k(const int* __restrict__ rowptr,
                                              const int* __restrict__ csr,
                                              const float* __restrict__ ea0,
                                              const float* __restrict__ ea1,
                                              float* __restrict__ dinv, int N,
                                              int E) {
  int i = blockIdx.x * TPB + threadIdx.x;
  int tn = 2 * N;
  if (i >= tn) return;
  int br = i >= N;
  const float* ea = br ? ea1 : ea0;
  int ebase = br * E;
  int s = rowptr[i], e = rowptr[i + 1];
  float d0 = 1.f, d1 = 1.f, d2 = 1.f, d3 = 1.f;
  for (int j = s; j < e; ++j) {
    int el = csr[j] - ebase;
    float4 w = *reinterpret_cast<const float4*>(&ea[(size_t)el * 4]);
    d0 += w.x; d1 += w.y; d2 += w.z; d3 += w.w;
  }
  float dO = (float)(e - s) + 1.f;
  dinv[0 * tn + i] = 1.f / sqrtf(d0);
  dinv[1 * tn + i] = 1.f / sqrtf(d1);
  dinv[2 * tn + i] = 1.f / sqrtf(d2);
  dinv[3 * tn + i] = 1.f / sqrtf(d3);
  dinv[4 * tn + i] = 1.f / sqrtf(dO);
}

__global__ __launch_bounds__(TPB) void eresolve2_k(
    const int* __restrict__ csr, const int* __restrict__ er0,
    const int* __restrict__ er1, const float* __restrict__ ea0,
    const float* __restrict__ ea1, const float* __restrict__ dinv, int N,
    int E, int* __restrict__ csrSrc, float4* __restrict__ csrW,
    float* __restrict__ csrWO) {
  int j = blockIdx.x * TPB + threadIdx.x;
  if (j >= 2 * E) return;
  int br = j >= E;
  int tn = 2 * N;
  int el = csr[j] - br * E;
  int rl = br ? er1[el] : er0[el];
  int gi = br * N + rl;
  const float* ea = br ? ea1 : ea0;
  float4 a = *reinterpret_cast<const float4*>(&ea[(size_t)el * 4]);
  csrSrc[j] = rl;
  csrW[j] = make_float4(a.x * dinv[gi], a.y * dinv[tn + gi],
                        a.z * dinv[2 * tn + gi], a.w * dinv[3 * tn + gi]);
  csrWO[j] = dinv[4 * tn + gi];
}

// ------------- fused 4-channel gather: 2 nodes/group, 2 neighbors each ------
__global__ __launch_bounds__(256) void gather4_k(
    const float4* __restrict__ X, const int* __restrict__ rowptr_b,
    const int* __restrict__ csrSrc, const float4* __restrict__ csrW,
    const float* __restrict__ dinvp, int tn, float4* __restrict__ S0,
    float4* __restrict__ S1, float4* __restrict__ S2, float4* __restrict__ S3) {
  int sb = swz_block(blockIdx.x, gridDim.x);
  int g = threadIdx.x >> 5;
  int l = threadIdx.x & 31;
  int nodeA = sb * 16 + g * 2;
  int nodeB = nodeA + 1;
  int sA = rowptr_b[nodeA], eA = rowptr_b[nodeA + 1];
  int sB = rowptr_b[nodeB], eB = rowptr_b[nodeB + 1];
  float dA0 = dinvp[nodeA], dA1 = dinvp[tn + nodeA], dA2 = dinvp[2 * tn + nodeA],
        dA3 = dinvp[3 * tn + nodeA];
  float dB0 = dinvp[nodeB], dB1 = dinvp[tn + nodeB], dB2 = dinvp[2 * tn + nodeB],
        dB3 = dinvp[3 * tn + nodeB];
  float4 xsA = X[(size_t)nodeA * 32 + l];
  float4 xsB = X[(size_t)nodeB * 32 + l];
  float4 aA0 = f4s(xsA, dA0), aA1 = f4s(xsA, dA1), aA2 = f4s(xsA, dA2), aA3 = f4s(xsA, dA3);
  float4 aB0 = f4s(xsB, dB0), aB1 = f4s(xsB, dB1), aB2 = f4s(xsB, dB2), aB3 = f4s(xsB, dB3);
  int jA = sA, jB = sB;
  // interleaved main loop: 2 neighbors per node per iteration (2 chains)
  while (jA + 1 < eA && jB + 1 < eB) {
    int rA0 = csrSrc[jA], rA1 = csrSrc[jA + 1];
    int rB0 = csrSrc[jB], rB1 = csrSrc[jB + 1];
    float4 wA0 = csrW[jA], wA1 = csrW[jA + 1];
    float4 wB0 = csrW[jB], wB1 = csrW[jB + 1];
    float4 xA0 = X[(size_t)rA0 * 32 + l];
    float4 xA1 = X[(size_t)rA1 * 32 + l];
    float4 xB0 = X[(size_t)rB0 * 32 + l];
    float4 xB1 = X[(size_t)rB1 * 32 + l];
    f4fma(aA0, xA0, wA0.x); f4fma(aA1, xA0, wA0.y); f4fma(aA2, xA0, wA0.z); f4fma(aA3, xA0, wA0.w);
    f4fma(aA0, xA1, wA1.x); f4fma(aA1, xA1, wA1.y); f4fma(aA2, xA1, wA1.z); f4fma(aA3, xA1, wA1.w);
    f4fma(aB0, xB0, wB0.x); f4fma(aB1, xB0, wB0.y); f4fma(aB2, xB0, wB0.z); f4fma(aB3, xB0, wB0.w);
    f4fma(aB0, xB1, wB1.x); f4fma(aB1, xB1, wB1.y); f4fma(aB2, xB1, wB1.z); f4fma(aB3, xB1, wB1.w);
    jA += 2; jB += 2;
  }
  // drain A (same bodies as R12: 4-way then scalar; ascending order preserved)
  for (; jA + 3 < eA; jA += 4) {
    int r0 = csrSrc[jA], r1 = csrSrc[jA + 1], r2 = csrSrc[jA + 2], r3 = csrSrc[jA + 3];
    float4 w0 = csrW[jA], w1 = csrW[jA + 1], w2 = csrW[jA + 2], w3 = csrW[jA + 3];
    float4 x0 = X[(size_t)r0 * 32 + l];
    float4 x1 = X[(size_t)r1 * 32 + l];
    float4 x2 = X[(size_t)r2 * 32 + l];
    float4 x3 = X[(size_t)r3 * 32 + l];
    f4fma(aA0, x0, w0.x); f4fma(aA1, x0, w0.y); f4fma(aA2, x0, w0.z); f4fma(aA3, x0, w0.w);
    f4fma(aA0, x1, w1.x); f4fma(aA1, x1, w1.y); f4fma(aA2, x1, w1.z); f4fma(aA3, x1, w1.w);
    f4fma(aA0, x2, w2.x); f4fma(aA1, x2, w2.y); f4fma(aA2, x2, w2.z); f4fma(aA3, x2, w2.w);
    f4fma(aA0, x3, w3.x); f4fma(aA1, x3, w3.y); f4fma(aA2, x3, w3.z); f4fma(aA3, x3, w3.w);
  }
  for (; jA < eA; ++jA) {
    int r = csrSrc[jA];
    float4 w = csrW[jA];
    float4 xr = X[(size_t)r * 32 + l];
    f4fma(aA0, xr, w.x); f4fma(aA1, xr, w.y); f4fma(aA2, xr, w.z); f4fma(aA3, xr, w.w);
  }
  // drain B
  for (; jB + 3 < eB; jB += 4) {
    int r0 = csrSrc[jB], r1 = csrSrc[jB + 1], r2 = csrSrc[jB + 2], r3 = csrSrc[jB + 3];
    float4 w0 = csrW[jB], w1 = csrW[jB + 1], w2 = csrW[jB + 2], w3 = csrW[jB + 3];
    float4 x0 = X[(size_t)r0 * 32 + l];
    float4 x1 = X[(size_t)r1 * 32 + l];
    float4 x2 = X[(size_t)r2 * 32 + l];
    float4 x3 = X[(size_t)r3 * 32 + l];
    f4fma(aB0, x0, w0.x); f4fma(aB1, x0, w0.y); f4fma(aB2, x0, w0.z); f4fma(aB3, x0, w0.w);
    f4fma(aB0, x1, w1.x); f4fma(aB1, x1, w1.y); f4fma(aB2, x1, w1.z); f4fma(aB3, x1, w1.w);
    f4fma(aB0, x2, w2.x); f4fma(aB1, x2, w2.y); f4fma(aB2, x2, w2.z); f4fma(aB3, x2, w2.w);
    f4fma(aB0, x3, w3.x); f4fma(aB1, x3, w3.y); f4fma(aB2, x3, w3.z); f4fma(aB3, x3, w3.w);
  }
  for (; jB < eB; ++jB) {
    int r = csrSrc[jB];
    float4 w = csrW[jB];
    float4 xr = X[(size_t)r * 32 + l];
    f4fma(aB0, xr, w.x); f4fma(aB1, xr, w.y); f4fma(aB2, xr, w.z); f4fma(aB3, xr, w.w);
  }
  size_t oA = (size_t)nodeA * 32 + l;
  size_t oB = (size_t)nodeB * 32 + l;
  S0[oA] = f4s(aA0, dA0); S1[oA] = f4s(aA1, dA1);
  S2[oA] = f4s(aA2, dA2); S3[oA] = f4s(aA3, dA3);
  S0[oB] = f4s(aB0, dB0); S1[oB] = f4s(aB1, dB1);
  S2[oB] = f4s(aB2, dB2); S3[oB] = f4s(aB3, dB3);
}

// ------------- single-channel gather: 2 nodes/group, 4 neighbors each -------
__global__ __launch_bounds__(256) void gather1_k(
    const float4* __restrict__ X, const int* __restrict__ rowptr_b,
    const int* __restrict__ csrSrc, const float* __restrict__ csrWO,
    const float* __restrict__ dinvO, int N, float4* __restrict__ Out) {
  int sb = swz_block(blockIdx.x, gridDim.x);
  int g = threadIdx.x >> 5;
  int l = threadIdx.x & 31;
  int nodeA = sb * 16 + g * 2;
  int nodeB = nodeA + 1;
  int sA = rowptr_b[nodeA], eA = rowptr_b[nodeA + 1];
  int sB = rowptr_b[nodeB], eB = rowptr_b[nodeB + 1];
  float diA = dinvO[nodeA], diB = dinvO[nodeB];
  float4 accA = f4s(X[(size_t)nodeA * 32 + l], diA);
  float4 accB = f4s(X[(size_t)nodeB * 32 + l], diB);
  int jA = sA, jB = sB;
  while (jA + 3 < eA && jB + 3 < eB) {
    int rA0 = csrSrc[jA], rA1 = csrSrc[jA + 1], rA2 = csrSrc[jA + 2], rA3 = csrSrc[jA + 3];
    int rB0 = csrSrc[jB], rB1 = csrSrc[jB + 1], rB2 = csrSrc[jB + 2], rB3 = csrSrc[jB + 3];
    float wA0 = csrWO[jA], wA1 = csrWO[jA + 1], wA2 = csrWO[jA + 2], wA3 = csrWO[jA + 3];
    float wB0 = csrWO[jB], wB1 = csrWO[jB + 1], wB2 = csrWO[jB + 2], wB3 = csrWO[jB + 3];
    float4 xA0 = X[(size_t)rA0 * 32 + l];
    float4 xA1 = X[(size_t)rA1 * 32 + l];
    float4 xA2 = X[(size_t)rA2 * 32 + l];
    float4 xA3 = X[(size_t)rA3 * 32 + l];
    float4 xB0 = X[(size_t)rB0 * 32 + l];
    float4 xB1 = X[(size_t)rB1 * 32 + l];
    float4 xB2 = X[(size_t)rB2 * 32 + l];
    float4 xB3 = X[(size_t)rB3 * 32 + l];
    f4fma(accA, xA0, wA0); f4fma(accA, xA1, wA1); f4fma(accA, xA2, wA2); f4fma(accA, xA3, wA3);
    f4fma(accB, xB0, wB0); f4fma(accB, xB1, wB1); f4fma(accB, xB2, wB2); f4fma(accB, xB3, wB3);
    jA += 4; jB += 4;
  }
  for (; jA + 3 < eA; jA += 4) {
    int r0 = csrSrc[jA], r1 = csrSrc[jA + 1], r2 = csrSrc[jA + 2], r3 = csrSrc[jA + 3];
    float w0 = csrWO[jA], w1 = csrWO[jA + 1], w2 = csrWO[jA + 2], w3 = csrWO[jA + 3];
    float4 x0 = X[(size_t)r0 * 32 + l];
    float4 x1 = X[(size_t)r1 * 32 + l];
    float4 x2 = X[(size_t)r2 * 32 + l];
    float4 x3 = X[(size_t)r3 * 32 + l];
    f4fma(accA, x0, w0); f4fma(accA, x1, w1); f4fma(accA, x2, w2); f4fma(accA, x3, w3);
  }
  for (; jA < eA; ++jA) {
    f4fma(accA, X[(size_t)csrSrc[jA] * 32 + l], csrWO[jA]);
  }
  for (; jB + 3 < eB; jB += 4) {
    int r0 = csrSrc[jB], r1 = csrSrc[jB + 1], r2 = csrSrc[jB + 2], r3 = csrSrc[jB + 3];
    float w0 = csrWO[jB], w1 = csrWO[jB + 1], w2 = csrWO[jB + 2], w3 = csrWO[jB + 3];
    float4 x0 = X[(size_t)r0 * 32 + l];
    float4 x1 = X[(size_t)r1 * 32 + l];
    float4 x2 = X[(size_t)r2 * 32 + l];
    float4 x3 = X[(size_t)r3 * 32 + l];
    f4fma(accB, x0, w0); f4fma(accB, x1, w1); f4fma(accB, x2, w2); f4fma(accB, x3, w3);
  }
  for (; jB < eB; ++jB) {
    f4fma(accB, X[(size_t)csrSrc[jB] * 32 + l], csrWO[jB]);
  }
  Out[(size_t)nodeA * 32 + l] = f4s(accA, diA);
  Out[(size_t)nodeB * 32 + l] = f4s(accB, diB);
}

// ---------------- GEMM with bias(+relu) epilogue (exact R4) ----------------
template <bool RELU>
__global__ __launch_bounds__(256) void gemm_epi(const float* __restrict__ A,
                                                const float* __restrict__ W,
                                                const float* __restrict__ bias,
                                                float* __restrict__ C, int M) {
  __shared__ float As[64][64];
  __shared__ float Ws[64][128];
  int tid = threadIdx.x;
  int tx = tid & 31;
  int ty = tid >> 5;
  int rowBase = blockIdx.x * 64;
  float acc[8][4] = {};
  for (int kc = 0; kc < 128; kc += 64) {
#pragma unroll
    for (int i = 0; i < 4; ++i) {
      int idx = tid + i * 256;
      int r = idx >> 4;
      int c4 = idx & 15;
      *reinterpret_cast<float4*>(&As[r][c4 * 4]) =
          *reinterpret_cast<const float4*>(&A[(size_t)(rowBase + r) * 128 + kc + c4 * 4]);
    }
#pragma unroll
    for (int i = 0; i < 8; ++i) {
      int idx = tid + i * 256;
      int r = idx >> 5;
      int c4 = idx & 31;
      *reinterpret_cast<float4*>(&Ws[r][c4 * 4]) =
          *reinterpret_cast<const float4*>(&W[(size_t)(kc + r) * 128 + c4 * 4]);
    }
    __syncthreads();
#pragma unroll 4
    for (int k = 0; k < 64; ++k) {
      float b0[4];
      *reinterpret_cast<float4*>(b0) = *reinterpret_cast<const float4*>(&Ws[k][tx * 4]);
#pragma unroll
      for (int j = 0; j < 8; ++j) {
        float a = As[ty * 8 + j][k];
        acc[j][0] += a * b0[0];
        acc[j][1] += a * b0[1];
        acc[j][2] += a * b0[2];
        acc[j][3] += a * b0[3];
      }
    }
    __syncthreads();
  }
  float4 bq = *reinterpret_cast<const float4*>(&bias[tx * 4]);
#pragma unroll
  for (int j = 0; j < 8; ++j) {
    float v0 = acc[j][0] + bq.x, v1 = acc[j][1] + bq.y, v2 = acc[j][2] + bq.z,
          v3 = acc[j][3] + bq.w;
    if (RELU) {
      v0 = fmaxf(v0, 0.f); v1 = fmaxf(v1, 0.f); v2 = fmaxf(v2, 0.f); v3 = fmaxf(v3, 0.f);
    }
    size_t r = (size_t)(rowBase + ty * 8 + j) * 128 + tx * 4;
    *reinterpret_cast<float4*>(&C[r]) = make_float4(v0, v1, v2, v3);
  }
}

// ---------------- gemm4 (exact R4): g1 = 0.25 * sum_q relu(S_q @ W_q + b_q) ---
__global__ __launch_bounds__(256) void gemm4_k(
    const float* __restrict__ S0, const float* __restrict__ S1,
    const float* __restrict__ S2, const float* __restrict__ S3,
    const float* __restrict__ W0, const float* __restrict__ W1,
    const float* __restrict__ W2, const float* __restrict__ W3,
    const float* __restrict__ B0, const float* __restrict__ B1,
    const float* __restrict__ B2, const float* __restrict__ B3,
    float* __restrict__ g1, int M) {
  __shared__ float As[64][64];
  __shared__ float Ws[64][128];
  const float* Sarr[4] = {S0, S1, S2, S3};
  const float* Warr[4] = {W0, W1, W2, W3};
  const float* Barr[4] = {B0, B1, B2, B3};
  int tid = threadIdx.x;
  int tx = tid & 31;
  int ty = tid >> 5;
  int rowBase = blockIdx.x * 64;
  float facc[8][4] = {};
#pragma unroll
  for (int q = 0; q < 4; ++q) {
    const float* A = Sarr[q];
    const float* W = Warr[q];
    float acc[8][4] = {};
    for (int kc = 0; kc < 128; kc += 64) {
#pragma unroll
      for (int i = 0; i < 4; ++i) {
        int idx = tid + i * 256;
        int r = idx >> 4;
        int c4 = idx & 15;
        *reinterpret_cast<float4*>(&As[r][c4 * 4]) =
            *reinterpret_cast<const float4*>(&A[(size_t)(rowBase + r) * 128 + kc + c4 * 4]);
      }
#pragma unroll
      for (int i = 0; i < 8; ++i) {
        int idx = tid + i * 256;
        int r = idx >> 5;
        int c4 = idx & 31;
        *reinterpret_cast<float4*>(&Ws[r][c4 * 4]) =
            *reinterpret_cast<const float4*>(&W[(size_t)(kc + r) * 128 + c4 * 4]);
      }
      __syncthreads();
#pragma unroll 4
      for (int k = 0; k < 64; ++k) {
        float b0[4];
        *reinterpret_cast<float4*>(b0) = *reinterpret_cast<const float4*>(&Ws[k][tx * 4]);
#pragma unroll
        for (int j = 0; j < 8; ++j) {
          float a = As[ty * 8 + j][k];
          acc[j][0] += a * b0[0];
          acc[j][1] += a * b0[1];
          acc[j][2] += a * b0[2];
          acc[j][3] += a * b0[3];
        }
      }
      __syncthreads();
    }
    float4 bq = *reinterpret_cast<const float4*>(&Barr[q][tx * 4]);
#pragma unroll
    for (int j = 0; j < 8; ++j) {
      facc[j][0] += fmaxf(acc[j][0] + bq.x, 0.f) * 0.25f;
      facc[j][1] += fmaxf(acc[j][1] + bq.y, 0.f) * 0.25f;
      facc[j][2] += fmaxf(acc[j][2] + bq.z, 0.f) * 0.25f;
      facc[j][3] += fmaxf(acc[j][3] + bq.w, 0.f) * 0.25f;
    }
  }
#pragma unroll
  for (int j = 0; j < 8; ++j) {
    size_t r = (size_t)(rowBase + ty * 8 + j) * 128 + tx * 4;
    *reinterpret_cast<float4*>(&g1[r]) =
        make_float4(facc[j][0], facc[j][1], facc[j][2], facc[j][3]);
  }
}

// ------------- score -------------
__global__ __launch_bounds__(256) void score_a(
    const float* __restrict__ g1, const float* __restrict__ g2,
    const float* __restrict__ g3, const float* __restrict__ Wrel,
    const float* __restrict__ Wroot, float* __restrict__ trel,
    float* __restrict__ troot, int N) {
  int wave = threadIdx.x >> 6;
  int lane = threadIdx.x & 63;
  int node = blockIdx.x * 4 + wave;
  if (node >= N) return;
  float sr = 0.f, so = 0.f;
#pragma unroll
  for (int t = 0; t < 2; ++t) {
    int f = lane + t * 64;
    float v1 = g1[(size_t)node * 128 + f];
    float v2 = g2[(size_t)node * 128 + f];
    float v3 = g3[(size_t)node * 128 + f];
    sr += v1 * Wrel[f] + v2 * Wrel[128 + f] + v3 * Wrel[256 + f];
    so += v1 * Wroot[f] + v2 * Wroot[128 + f] + v3 * Wroot[256 + f];
  }
  for (int off = 32; off; off >>= 1) {
    sr += __shfl_down(sr, off);
    so += __shfl_down(so, off);
  }
  if (lane == 0) { trel[node] = sr; troot[node] = so; }
}

__global__ __launch_bounds__(TPB) void score_b(
    const int* __restrict__ rowptr_b, const int* __restrict__ csrSrc,
    const float* __restrict__ trel, const float* __restrict__ troot,
    const float* __restrict__ bs, float* __restrict__ score, int N) {
  int i = blockIdx.x * TPB + threadIdx.x;
  if (i >= N) return;
  float sc = bs[0] + troot[i];
  int s = rowptr_b[i], e = rowptr_b[i + 1];
  for (int j = s; j < e; ++j) sc += trel[csrSrc[j]];
  score[i] = sc;
}

// ------------- per-graph top-k (bitonic) + tanh-weighted mean pool -------------
__global__ __launch_bounds__(512) void topk_pool(
    const float* __restrict__ score, const float* __restrict__ g1,
    const float* __restrict__ g2, const float* __restrict__ g3,
    float* __restrict__ r, int half, int npg, int k) {
  __shared__ float key[1024];
  __shared__ int idx[1024];
  __shared__ float wts[512];
  int b = blockIdx.x;
  int tid = threadIdx.x;
  int base = b * npg;
  for (int i = tid; i < 1024; i += 512) {
    key[i] = (i < npg) ? score[base + i] : -3.0e38f;
    idx[i] = i;
  }
  __syncthreads();
  for (int kk = 2; kk <= 1024; kk <<= 1) {
    for (int j = kk >> 1; j > 0; j >>= 1) {
      for (int i = tid; i < 1024; i += 512) {
        int ixj = i ^ j;
        if (ixj > i) {
          bool desc = ((i & kk) == 0);
          float ki = key[i], kj = key[ixj];
          bool sw = desc ? (ki < kj) : (ki > kj);
          if (sw) {
            key[i] = kj; key[ixj] = ki;
            int t = idx[i]; idx[i] = idx[ixj]; idx[ixj] = t;
          }
        }
      }
      __syncthreads();
    }
  }
  if (tid < k) wts[tid] = tanhf(key[tid]);
  __syncthreads();
  if (tid < 384) {
    const float* gp = (tid < 128) ? g1 : ((tid < 256) ? g2 : g3);
    int fo = tid & 127;
    float acc = 0.f;
    for (int j = 0; j < k; ++j) {
      int n = base + idx[j];
      acc += wts[j] * gp[(size_t)n * 128 + fo];
    }
    r[(size_t)b * 768 + half * 384 + tid] = acc / (float)k;
  }
}

// ------------- MLP 768 -> 32 -> 8 -> 2 -------------
__global__ __launch_bounds__(64) void mlp_k(
    const float* __restrict__ r, const float* __restrict__ Wm1,
    const float* __restrict__ bm1, const float* __restrict__ Wm2,
    const float* __restrict__ bm2, const float* __restrict__ Wm3,
    const float* __restrict__ bm3, float* __restrict__ out) {
  __shared__ float rr[768];
  __shared__ float h1[32];
  __shared__ float h2[8];
  int b = blockIdx.x;
  int tid = threadIdx.x;
  for (int i = tid; i < 768; i += 64) rr[i] = r[(size_t)b * 768 + i];
  __syncthreads();
  if (tid < 32) {
    float s = bm1[tid];
    for (int i = 0; i < 768; ++i) s += rr[i] * Wm1[i * 32 + tid];
    h1[tid] = fmaxf(s, 0.f);
  }
  __syncthreads();
  if (tid < 8) {
    float s = bm2[tid];
    for (int i = 0; i < 32; ++i) s += h1[i] * Wm2[i * 8 + tid];
    h2[tid] = fmaxf(s, 0.f);
  }
  __syncthreads();
  if (tid < 2) {
    float s = bm3[tid];
    for (int i = 0; i < 8; ++i) s += h2[i] * Wm3[i * 2 + tid];
    out[b * 2 + tid] = s;
  }
}

// ---------------------------------------------------------------------------
extern "C" void kernel_launch(void* const* d_in, const int* in_sizes, int n_in,
                              void* d_out, int out_size, void* d_ws, size_t ws_size,
                              hipStream_t stream) {
  const float* x[2]  = {(const float*)d_in[0], (const float*)d_in[3]};
  const float* eat[2] = {(const float*)d_in[1], (const float*)d_in[4]};
  const int*   ei[2] = {(const int*)d_in[2], (const int*)d_in[5]};
  const int N = in_sizes[0] / 128;   // 64000
  const int E = in_sizes[2] / 2;     // 512000
  const int tn = 2 * N;
  const int tE = 2 * E;
  const int Bg = 64;
  const int npg = N / Bg;            // 1000
  const int kq = npg / 2;            // 500

  const float* W1[4] = {(const float*)d_in[9], (const float*)d_in[11],
                        (const float*)d_in[13], (const float*)d_in[15]};
  const float* b1[4] = {(const float*)d_in[10], (const float*)d_in[12],
                        (const float*)d_in[14], (const float*)d_in[16]};
  const float* W2 = (const float*)d_in[17];
  const float* b2 = (const float*)d_in[18];
  const float* W3 = (const float*)d_in[19];
  const float* b3 = (const float*)d_in[20];
  const float* Wsrel  = (const float*)d_in[21];
  const float* bsrel  = (const float*)d_in[22];
  const float* Wsroot = (const float*)d_in[23];
  const float* Wm1 = (const float*)d_in[24];
  const float* bm1 = (const float*)d_in[25];
  const float* Wm2 = (const float*)d_in[26];
  const float* bm2 = (const float*)d_in[27];
  const float* Wm3 = (const float*)d_in[28];
  const float* bm3 = (const float*)d_in[29];
  float* out = (float*)d_out;

  // workspace carve
  char* ws = (char*)d_ws;
  size_t off = 0;
  auto alloc = [&](size_t bytes) -> void* {
    void* p = ws + off;
    off = (off + bytes + 511) & ~(size_t)511;
    return p;
  };
  const size_t nf = (size_t)N * 128 * sizeof(float);
  float* P0 = (float*)alloc(nf);   // S0 / agg
  float* P1 = (float*)alloc(nf);   // S1 / g2
  float* P2 = (float*)alloc(nf);   // S2 / g3
  float* P3 = (float*)alloc(nf);   // S3
  float* P4 = (float*)alloc(nf);   // g1
  float* dinv = (float*)alloc((size_t)5 * tn * sizeof(float));
  float* trel = (float*)alloc((size_t)N * sizeof(float));
  float* trot = (float*)alloc((size_t)N * sizeof(float));
  float* sco  = (float*)alloc((size_t)N * sizeof(float));
  int* rowptr = (int*)alloc((size_t)(tn + 1) * sizeof(int));
  int* cnt    = (int*)alloc((size_t)tn * sizeof(int));
  int* csr    = (int*)alloc((size_t)tE * sizeof(int));
  int* csrSrc = (int*)alloc((size_t)tE * sizeof(int));
  float4* csrW = (float4*)alloc((size_t)tE * sizeof(float4));
  float* csrWO = (float*)alloc((size_t)tE * sizeof(float));
  int* bsum   = (int*)alloc(1024);
  float* rbuf = (float*)alloc((size_t)Bg * 768 * sizeof(float));
  if (off > ws_size) return;

  const int nbN2 = (tn + TPB - 1) / TPB;    // 500
  const int nbE2 = (tE + TPB - 1) / TPB;    // 4000
  const int nbS  = (tn + 511) / 512;        // 250
  const int nbN  = (N + TPB - 1) / TPB;     // 250
  const int nbGather = N / 16;              // 4000 (divisible by 8)
  const int nbGemm = N / 64;                // 1000

  // ---- merged CSR build for both branches ----
  hipMemsetAsync(cnt, 0, (size_t)tn * sizeof(int), stream);
  count2_k<<<nbE2, TPB, 0, stream>>>(ei[0] + E, ei[1] + E, cnt, N, E);
  scan1_k<<<nbS, 512, 0, stream>>>(cnt, rowptr, bsum, tn);
  scan2_k<<<1, TPB, 0, stream>>>(bsum, nbS);
  scan3_k<<<nbS, 512, 0, stream>>>(rowptr, bsum, tn, tE);
  hipMemsetAsync(cnt, 0, (size_t)tn * sizeof(int), stream);
  fill2_k<<<nbE2, TPB, 0, stream>>>(ei[0] + E, ei[1] + E, rowptr, cnt, csr, N, E);
  sortadj_k<<<nbN2, TPB, 0, stream>>>(rowptr, csr, tn);
  deg2_k<<<nbN2, TPB, 0, stream>>>(rowptr, csr, eat[0], eat[1], dinv, N, E);
  eresolve2_k<<<nbE2, TPB, 0, stream>>>(csr, ei[0], ei[1], eat[0], eat[1],
                                        dinv, N, E, csrSrc, csrW, csrWO);

  for (int br = 0; br < 2; ++br) {
    const int* rowptr_b = rowptr + (size_t)br * N;
    const float* dinvp = dinv + (size_t)br * N;
    const float* dinvO = dinv + (size_t)4 * tn + (size_t)br * N;

    // conv1
    gather4_k<<<nbGather, 256, 0, stream>>>(
        (const float4*)x[br], rowptr_b, csrSrc, csrW, dinvp, tn,
        (float4*)P0, (float4*)P1, (float4*)P2, (float4*)P3);
    gemm4_k<<<nbGemm, 256, 0, stream>>>(P0, P1, P2, P3,
                                        W1[0], W1[1], W1[2], W1[3],
                                        b1[0], b1[1], b1[2], b1[3], P4, N);

    // conv2
    gather1_k<<<nbGather, 256, 0, stream>>>(
        (const float4*)P4, rowptr_b, csrSrc, csrWO, dinvO, N, (float4*)P0);
    gemm_epi<true><<<nbGemm, 256, 0, stream>>>(P0, W2, b2, P1, N);

    // conv3
    gather1_k<<<nbGather, 256, 0, stream>>>(
        (const float4*)P1, rowptr_b, csrSrc, csrWO, dinvO, N, (float4*)P0);
    gemm_epi<false><<<nbGemm, 256, 0, stream>>>(P0, W3, b3, P2, N);

    // score + top-k pool (g1=P4, g2=P1, g3=P2)
    score_a<<<(N + 3) / 4, 256, 0, stream>>>(P4, P1, P2, Wsrel, Wsroot, trel, trot, N);
    score_b<<<nbN, TPB, 0, stream>>>(rowptr_b, csrSrc, trel, trot, bsrel, sco, N);
    topk_pool<<<Bg, 512, 0, stream>>>(sco, P4, P1, P2, rbuf, br, npg, kq);
  }

  mlp_k<<<Bg, 64, 0, stream>>>(rbuf, Wm1, bm1, Wm2, bm2, Wm3, bm3, out);
}

// Round 14
// 890.938 us; speedup vs baseline: 1.0189x; 1.0189x over previous
//
#include <hip/hip_runtime.h>
#include <math.h>

// ---------------------------------------------------------------------------
// PGCN twin-branch GCN. fp32. R14 = exact R12 (best verified: 901.8 us).
// Merged CSR, 4-way gathers, R4 GEMMs, fused topk_pool. absmax 0.
// ---------------------------------------------------------------------------

#define TPB 256

__device__ __forceinline__ int swz_block(int bid, int nb) {
  return (bid & 7) * (nb >> 3) + (bid >> 3);
}

__device__ __forceinline__ void f4fma(float4& a, const float4 b, float s) {
  a.x += b.x * s; a.y += b.y * s; a.z += b.z * s; a.w += b.w * s;
}
__device__ __forceinline__ float4 f4s(const float4 a, float s) {
  return make_float4(a.x * s, a.y * s, a.z * s, a.w * s);
}

// ---------------- merged CSR build (both branches, concatenated) ------------
__global__ __launch_bounds__(TPB) void count2_k(const int* __restrict__ ec0,
                                                const int* __restrict__ ec1,
                                                int* __restrict__ cnt, int N,
                                                int E) {
  int e = blockIdx.x * TPB + threadIdx.x;
  if (e < 2 * E) {
    int br = e >= E;
    int el = e - br * E;
    int c = (br ? ec1[el] : ec0[el]) + br * N;
    atomicAdd(&cnt[c], 1);
  }
}

__global__ __launch_bounds__(512) void scan1_k(const int* __restrict__ cnt,
                                               int* __restrict__ rowptr,
                                               int* __restrict__ bsum, int tn) {
  __shared__ int s[512];
  int tid = threadIdx.x;
  int gid = blockIdx.x * 512 + tid;
  int v = (gid < tn) ? cnt[gid] : 0;
  s[tid] = v;
  __syncthreads();
  for (int o = 1; o < 512; o <<= 1) {
    int t = (tid >= o) ? s[tid - o] : 0;
    __syncthreads();
    s[tid] += t;
    __syncthreads();
  }
  if (gid < tn) rowptr[gid] = s[tid] - v;
  if (tid == 511) bsum[blockIdx.x] = s[511];
}

__global__ __launch_bounds__(TPB) void scan2_k(int* __restrict__ bsum, int nb) {
  __shared__ int s[TPB];
  int tid = threadIdx.x;
  int v = (tid < nb) ? bsum[tid] : 0;
  s[tid] = v;
  __syncthreads();
  for (int o = 1; o < TPB; o <<= 1) {
    int t = (tid >= o) ? s[tid - o] : 0;
    __syncthreads();
    s[tid] += t;
    __syncthreads();
  }
  if (tid < nb) bsum[tid] = s[tid] - v;
}

__global__ __launch_bounds__(512) void scan3_k(int* __restrict__ rowptr,
                                               const int* __restrict__ bsum,
                                               int tn, int tE) {
  int gid = blockIdx.x * 512 + threadIdx.x;
  if (gid < tn) rowptr[gid] += bsum[blockIdx.x];
  if (gid == 0) rowptr[tn] = tE;
}

__global__ __launch_bounds__(TPB) void fill2_k(const int* __restrict__ ec0,
                                               const int* __restrict__ ec1,
                                               const int* __restrict__ rowptr,
                                               int* __restrict__ fil,
                                               int* __restrict__ csr, int N,
                                               int E) {
  int e = blockIdx.x * TPB + threadIdx.x;
  if (e < 2 * E) {
    int br = e >= E;
    int el = e - br * E;
    int c = (br ? ec1[el] : ec0[el]) + br * N;
    int p = rowptr[c] + atomicAdd(&fil[c], 1);
    csr[p] = e;
  }
}

__global__ __launch_bounds__(TPB) void sortadj_k(const int* __restrict__ rowptr,
                                                 int* __restrict__ csr, int tn) {
  int i = blockIdx.x * TPB + threadIdx.x;
  if (i >= tn) return;
  int s = rowptr[i], e = rowptr[i + 1];
  for (int a = s + 1; a < e; ++a) {
    int v = csr[a];
    int b = a - 1;
    while (b >= s && csr[b] > v) { csr[b + 1] = csr[b]; --b; }
    csr[b + 1] = v;
  }
}

__global__ __launch_bounds__(TPB) void deg2_k(const int* __restrict__ rowptr,
                                              const int* __restrict__ csr,
                                              const float* __restrict__ ea0,
                                              const float* __restrict__ ea1,
                                              float* __restrict__ dinv, int N,
                                              int E) {
  int i = blockIdx.x * TPB + threadIdx.x;
  int tn = 2 * N;
  if (i >= tn) return;
  int br = i >= N;
  const float* ea = br ? ea1 : ea0;
  int ebase = br * E;
  int s = rowptr[i], e = rowptr[i + 1];
  float d0 = 1.f, d1 = 1.f, d2 = 1.f, d3 = 1.f;
  for (int j = s; j < e; ++j) {
    int el = csr[j] - ebase;
    float4 w = *reinterpret_cast<const float4*>(&ea[(size_t)el * 4]);
    d0 += w.x; d1 += w.y; d2 += w.z; d3 += w.w;
  }
  float dO = (float)(e - s) + 1.f;
  dinv[0 * tn + i] = 1.f / sqrtf(d0);
  dinv[1 * tn + i] = 1.f / sqrtf(d1);
  dinv[2 * tn + i] = 1.f / sqrtf(d2);
  dinv[3 * tn + i] = 1.f / sqrtf(d3);
  dinv[4 * tn + i] = 1.f / sqrtf(dO);
}

__global__ __launch_bounds__(TPB) void eresolve2_k(
    const int* __restrict__ csr, const int* __restrict__ er0,
    const int* __restrict__ er1, const float* __restrict__ ea0,
    const float* __restrict__ ea1, const float* __restrict__ dinv, int N,
    int E, int* __restrict__ csrSrc, float4* __restrict__ csrW,
    float* __restrict__ csrWO) {
  int j = blockIdx.x * TPB + threadIdx.x;
  if (j >= 2 * E) return;
  int br = j >= E;
  int tn = 2 * N;
  int el = csr[j] - br * E;
  int rl = br ? er1[el] : er0[el];
  int gi = br * N + rl;
  const float* ea = br ? ea1 : ea0;
  float4 a = *reinterpret_cast<const float4*>(&ea[(size_t)el * 4]);
  csrSrc[j] = rl;
  csrW[j] = make_float4(a.x * dinv[gi], a.y * dinv[tn + gi],
                        a.z * dinv[2 * tn + gi], a.w * dinv[3 * tn + gi]);
  csrWO[j] = dinv[4 * tn + gi];
}

// ------------- fused 4-channel gather (4-way batched, R10-proven) ----------
__global__ __launch_bounds__(256) void gather4_k(
    const float4* __restrict__ X, const int* __restrict__ rowptr_b,
    const int* __restrict__ csrSrc, const float4* __restrict__ csrW,
    const float* __restrict__ dinvp, int tn, float4* __restrict__ S0,
    float4* __restrict__ S1, float4* __restrict__ S2, float4* __restrict__ S3) {
  int sb = swz_block(blockIdx.x, gridDim.x);
  int node = sb * 8 + (threadIdx.x >> 5);
  int l = threadIdx.x & 31;
  int s = rowptr_b[node], e = rowptr_b[node + 1];
  float d0 = dinvp[node], d1 = dinvp[tn + node], d2 = dinvp[2 * tn + node],
        d3 = dinvp[3 * tn + node];
  float4 xs = X[(size_t)node * 32 + l];
  float4 a0 = f4s(xs, d0), a1 = f4s(xs, d1), a2 = f4s(xs, d2), a3 = f4s(xs, d3);
  int j = s;
  for (; j + 3 < e; j += 4) {
    int r0 = csrSrc[j], r1 = csrSrc[j + 1], r2 = csrSrc[j + 2], r3 = csrSrc[j + 3];
    float4 w0 = csrW[j], w1 = csrW[j + 1], w2 = csrW[j + 2], w3 = csrW[j + 3];
    float4 x0 = X[(size_t)r0 * 32 + l];
    float4 x1 = X[(size_t)r1 * 32 + l];
    float4 x2 = X[(size_t)r2 * 32 + l];
    float4 x3 = X[(size_t)r3 * 32 + l];
    f4fma(a0, x0, w0.x); f4fma(a1, x0, w0.y); f4fma(a2, x0, w0.z); f4fma(a3, x0, w0.w);
    f4fma(a0, x1, w1.x); f4fma(a1, x1, w1.y); f4fma(a2, x1, w1.z); f4fma(a3, x1, w1.w);
    f4fma(a0, x2, w2.x); f4fma(a1, x2, w2.y); f4fma(a2, x2, w2.z); f4fma(a3, x2, w2.w);
    f4fma(a0, x3, w3.x); f4fma(a1, x3, w3.y); f4fma(a2, x3, w3.z); f4fma(a3, x3, w3.w);
  }
  for (; j < e; ++j) {
    int r = csrSrc[j];
    float4 w = csrW[j];
    float4 xr = X[(size_t)r * 32 + l];
    f4fma(a0, xr, w.x); f4fma(a1, xr, w.y); f4fma(a2, xr, w.z); f4fma(a3, xr, w.w);
  }
  size_t o = (size_t)node * 32 + l;
  S0[o] = f4s(a0, d0);
  S1[o] = f4s(a1, d1);
  S2[o] = f4s(a2, d2);
  S3[o] = f4s(a3, d3);
}

// ------------- single-channel gather (4-way batched, R10-proven) ----------
__global__ __launch_bounds__(256) void gather1_k(
    const float4* __restrict__ X, const int* __restrict__ rowptr_b,
    const int* __restrict__ csrSrc, const float* __restrict__ csrWO,
    const float* __restrict__ dinvO, int N, float4* __restrict__ Out) {
  int sb = swz_block(blockIdx.x, gridDim.x);
  int node = sb * 8 + (threadIdx.x >> 5);
  int l = threadIdx.x & 31;
  int s = rowptr_b[node], e = rowptr_b[node + 1];
  float di = dinvO[node];
  float4 acc = f4s(X[(size_t)node * 32 + l], di);
  int j = s;
  for (; j + 3 < e; j += 4) {
    int r0 = csrSrc[j], r1 = csrSrc[j + 1], r2 = csrSrc[j + 2], r3 = csrSrc[j + 3];
    float w0 = csrWO[j], w1 = csrWO[j + 1], w2 = csrWO[j + 2], w3 = csrWO[j + 3];
    float4 x0 = X[(size_t)r0 * 32 + l];
    float4 x1 = X[(size_t)r1 * 32 + l];
    float4 x2 = X[(size_t)r2 * 32 + l];
    float4 x3 = X[(size_t)r3 * 32 + l];
    f4fma(acc, x0, w0); f4fma(acc, x1, w1); f4fma(acc, x2, w2); f4fma(acc, x3, w3);
  }
  for (; j < e; ++j) {
    f4fma(acc, X[(size_t)csrSrc[j] * 32 + l], csrWO[j]);
  }
  Out[(size_t)node * 32 + l] = f4s(acc, di);
}

// ---------------- GEMM with bias(+relu) epilogue (exact R4) ----------------
template <bool RELU>
__global__ __launch_bounds__(256) void gemm_epi(const float* __restrict__ A,
                                                const float* __restrict__ W,
                                                const float* __restrict__ bias,
                                                float* __restrict__ C, int M) {
  __shared__ float As[64][64];
  __shared__ float Ws[64][128];
  int tid = threadIdx.x;
  int tx = tid & 31;
  int ty = tid >> 5;
  int rowBase = blockIdx.x * 64;
  float acc[8][4] = {};
  for (int kc = 0; kc < 128; kc += 64) {
#pragma unroll
    for (int i = 0; i < 4; ++i) {
      int idx = tid + i * 256;
      int r = idx >> 4;
      int c4 = idx & 15;
      *reinterpret_cast<float4*>(&As[r][c4 * 4]) =
          *reinterpret_cast<const float4*>(&A[(size_t)(rowBase + r) * 128 + kc + c4 * 4]);
    }
#pragma unroll
    for (int i = 0; i < 8; ++i) {
      int idx = tid + i * 256;
      int r = idx >> 5;
      int c4 = idx & 31;
      *reinterpret_cast<float4*>(&Ws[r][c4 * 4]) =
          *reinterpret_cast<const float4*>(&W[(size_t)(kc + r) * 128 + c4 * 4]);
    }
    __syncthreads();
#pragma unroll 4
    for (int k = 0; k < 64; ++k) {
      float b0[4];
      *reinterpret_cast<float4*>(b0) = *reinterpret_cast<const float4*>(&Ws[k][tx * 4]);
#pragma unroll
      for (int j = 0; j < 8; ++j) {
        float a = As[ty * 8 + j][k];
        acc[j][0] += a * b0[0];
        acc[j][1] += a * b0[1];
        acc[j][2] += a * b0[2];
        acc[j][3] += a * b0[3];
      }
    }
    __syncthreads();
  }
  float4 bq = *reinterpret_cast<const float4*>(&bias[tx * 4]);
#pragma unroll
  for (int j = 0; j < 8; ++j) {
    float v0 = acc[j][0] + bq.x, v1 = acc[j][1] + bq.y, v2 = acc[j][2] + bq.z,
          v3 = acc[j][3] + bq.w;
    if (RELU) {
      v0 = fmaxf(v0, 0.f); v1 = fmaxf(v1, 0.f); v2 = fmaxf(v2, 0.f); v3 = fmaxf(v3, 0.f);
    }
    size_t r = (size_t)(rowBase + ty * 8 + j) * 128 + tx * 4;
    *reinterpret_cast<float4*>(&C[r]) = make_float4(v0, v1, v2, v3);
  }
}

// ---------------- gemm4 (exact R4): g1 = 0.25 * sum_q relu(S_q @ W_q + b_q) ---
__global__ __launch_bounds__(256) void gemm4_k(
    const float* __restrict__ S0, const float* __restrict__ S1,
    const float* __restrict__ S2, const float* __restrict__ S3,
    const float* __restrict__ W0, const float* __restrict__ W1,
    const float* __restrict__ W2, const float* __restrict__ W3,
    const float* __restrict__ B0, const float* __restrict__ B1,
    const float* __restrict__ B2, const float* __restrict__ B3,
    float* __restrict__ g1, int M) {
  __shared__ float As[64][64];
  __shared__ float Ws[64][128];
  const float* Sarr[4] = {S0, S1, S2, S3};
  const float* Warr[4] = {W0, W1, W2, W3};
  const float* Barr[4] = {B0, B1, B2, B3};
  int tid = threadIdx.x;
  int tx = tid & 31;
  int ty = tid >> 5;
  int rowBase = blockIdx.x * 64;
  float facc[8][4] = {};
#pragma unroll
  for (int q = 0; q < 4; ++q) {
    const float* A = Sarr[q];
    const float* W = Warr[q];
    float acc[8][4] = {};
    for (int kc = 0; kc < 128; kc += 64) {
#pragma unroll
      for (int i = 0; i < 4; ++i) {
        int idx = tid + i * 256;
        int r = idx >> 4;
        int c4 = idx & 15;
        *reinterpret_cast<float4*>(&As[r][c4 * 4]) =
            *reinterpret_cast<const float4*>(&A[(size_t)(rowBase + r) * 128 + kc + c4 * 4]);
      }
#pragma unroll
      for (int i = 0; i < 8; ++i) {
        int idx = tid + i * 256;
        int r = idx >> 5;
        int c4 = idx & 31;
        *reinterpret_cast<float4*>(&Ws[r][c4 * 4]) =
            *reinterpret_cast<const float4*>(&W[(size_t)(kc + r) * 128 + c4 * 4]);
      }
      __syncthreads();
#pragma unroll 4
      for (int k = 0; k < 64; ++k) {
        float b0[4];
        *reinterpret_cast<float4*>(b0) = *reinterpret_cast<const float4*>(&Ws[k][tx * 4]);
#pragma unroll
        for (int j = 0; j < 8; ++j) {
          float a = As[ty * 8 + j][k];
          acc[j][0] += a * b0[0];
          acc[j][1] += a * b0[1];
          acc[j][2] += a * b0[2];
          acc[j][3] += a * b0[3];
        }
      }
      __syncthreads();
    }
    float4 bq = *reinterpret_cast<const float4*>(&Barr[q][tx * 4]);
#pragma unroll
    for (int j = 0; j < 8; ++j) {
      facc[j][0] += fmaxf(acc[j][0] + bq.x, 0.f) * 0.25f;
      facc[j][1] += fmaxf(acc[j][1] + bq.y, 0.f) * 0.25f;
      facc[j][2] += fmaxf(acc[j][2] + bq.z, 0.f) * 0.25f;
      facc[j][3] += fmaxf(acc[j][3] + bq.w, 0.f) * 0.25f;
    }
  }
#pragma unroll
  for (int j = 0; j < 8; ++j) {
    size_t r = (size_t)(rowBase + ty * 8 + j) * 128 + tx * 4;
    *reinterpret_cast<float4*>(&g1[r]) =
        make_float4(facc[j][0], facc[j][1], facc[j][2], facc[j][3]);
  }
}

// ------------- score -------------
__global__ __launch_bounds__(256) void score_a(
    const float* __restrict__ g1, const float* __restrict__ g2,
    const float* __restrict__ g3, const float* __restrict__ Wrel,
    const float* __restrict__ Wroot, float* __restrict__ trel,
    float* __restrict__ troot, int N) {
  int wave = threadIdx.x >> 6;
  int lane = threadIdx.x & 63;
  int node = blockIdx.x * 4 + wave;
  if (node >= N) return;
  float sr = 0.f, so = 0.f;
#pragma unroll
  for (int t = 0; t < 2; ++t) {
    int f = lane + t * 64;
    float v1 = g1[(size_t)node * 128 + f];
    float v2 = g2[(size_t)node * 128 + f];
    float v3 = g3[(size_t)node * 128 + f];
    sr += v1 * Wrel[f] + v2 * Wrel[128 + f] + v3 * Wrel[256 + f];
    so += v1 * Wroot[f] + v2 * Wroot[128 + f] + v3 * Wroot[256 + f];
  }
  for (int off = 32; off; off >>= 1) {
    sr += __shfl_down(sr, off);
    so += __shfl_down(so, off);
  }
  if (lane == 0) { trel[node] = sr; troot[node] = so; }
}

__global__ __launch_bounds__(TPB) void score_b(
    const int* __restrict__ rowptr_b, const int* __restrict__ csrSrc,
    const float* __restrict__ trel, const float* __restrict__ troot,
    const float* __restrict__ bs, float* __restrict__ score, int N) {
  int i = blockIdx.x * TPB + threadIdx.x;
  if (i >= N) return;
  float sc = bs[0] + troot[i];
  int s = rowptr_b[i], e = rowptr_b[i + 1];
  for (int j = s; j < e; ++j) sc += trel[csrSrc[j]];
  score[i] = sc;
}

// ------------- per-graph top-k (bitonic) + tanh-weighted mean pool -------------
__global__ __launch_bounds__(512) void topk_pool(
    const float* __restrict__ score, const float* __restrict__ g1,
    const float* __restrict__ g2, const float* __restrict__ g3,
    float* __restrict__ r, int half, int npg, int k) {
  __shared__ float key[1024];
  __shared__ int idx[1024];
  __shared__ float wts[512];
  int b = blockIdx.x;
  int tid = threadIdx.x;
  int base = b * npg;
  for (int i = tid; i < 1024; i += 512) {
    key[i] = (i < npg) ? score[base + i] : -3.0e38f;
    idx[i] = i;
  }
  __syncthreads();
  for (int kk = 2; kk <= 1024; kk <<= 1) {
    for (int j = kk >> 1; j > 0; j >>= 1) {
      for (int i = tid; i < 1024; i += 512) {
        int ixj = i ^ j;
        if (ixj > i) {
          bool desc = ((i & kk) == 0);
          float ki = key[i], kj = key[ixj];
          bool sw = desc ? (ki < kj) : (ki > kj);
          if (sw) {
            key[i] = kj; key[ixj] = ki;
            int t = idx[i]; idx[i] = idx[ixj]; idx[ixj] = t;
          }
        }
      }
      __syncthreads();
    }
  }
  if (tid < k) wts[tid] = tanhf(key[tid]);
  __syncthreads();
  if (tid < 384) {
    const float* gp = (tid < 128) ? g1 : ((tid < 256) ? g2 : g3);
    int fo = tid & 127;
    float acc = 0.f;
    for (int j = 0; j < k; ++j) {
      int n = base + idx[j];
      acc += wts[j] * gp[(size_t)n * 128 + fo];
    }
    r[(size_t)b * 768 + half * 384 + tid] = acc / (float)k;
  }
}

// ------------- MLP 768 -> 32 -> 8 -> 2 -------------
__global__ __launch_bounds__(64) void mlp_k(
    const float* __restrict__ r, const float* __restrict__ Wm1,
    const float* __restrict__ bm1, const float* __restrict__ Wm2,
    const float* __restrict__ bm2, const float* __restrict__ Wm3,
    const float* __restrict__ bm3, float* __restrict__ out) {
  __shared__ float rr[768];
  __shared__ float h1[32];
  __shared__ float h2[8];
  int b = blockIdx.x;
  int tid = threadIdx.x;
  for (int i = tid; i < 768; i += 64) rr[i] = r[(size_t)b * 768 + i];
  __syncthreads();
  if (tid < 32) {
    float s = bm1[tid];
    for (int i = 0; i < 768; ++i) s += rr[i] * Wm1[i * 32 + tid];
    h1[tid] = fmaxf(s, 0.f);
  }
  __syncthreads();
  if (tid < 8) {
    float s = bm2[tid];
    for (int i = 0; i < 32; ++i) s += h1[i] * Wm2[i * 8 + tid];
    h2[tid] = fmaxf(s, 0.f);
  }
  __syncthreads();
  if (tid < 2) {
    float s = bm3[tid];
    for (int i = 0; i < 8; ++i) s += h2[i] * Wm3[i * 2 + tid];
    out[b * 2 + tid] = s;
  }
}

// ---------------------------------------------------------------------------
extern "C" void kernel_launch(void* const* d_in, const int* in_sizes, int n_in,
                              void* d_out, int out_size, void* d_ws, size_t ws_size,
                              hipStream_t stream) {
  const float* x[2]  = {(const float*)d_in[0], (const float*)d_in[3]};
  const float* eat[2] = {(const float*)d_in[1], (const float*)d_in[4]};
  const int*   ei[2] = {(const int*)d_in[2], (const int*)d_in[5]};
  const int N = in_sizes[0] / 128;   // 64000
  const int E = in_sizes[2] / 2;     // 512000
  const int tn = 2 * N;
  const int tE = 2 * E;
  const int Bg = 64;
  const int npg = N / Bg;            // 1000
  const int kq = npg / 2;            // 500

  const float* W1[4] = {(const float*)d_in[9], (const float*)d_in[11],
                        (const float*)d_in[13], (const float*)d_in[15]};
  const float* b1[4] = {(const float*)d_in[10], (const float*)d_in[12],
                        (const float*)d_in[14], (const float*)d_in[16]};
  const float* W2 = (const float*)d_in[17];
  const float* b2 = (const float*)d_in[18];
  const float* W3 = (const float*)d_in[19];
  const float* b3 = (const float*)d_in[20];
  const float* Wsrel  = (const float*)d_in[21];
  const float* bsrel  = (const float*)d_in[22];
  const float* Wsroot = (const float*)d_in[23];
  const float* Wm1 = (const float*)d_in[24];
  const float* bm1 = (const float*)d_in[25];
  const float* Wm2 = (const float*)d_in[26];
  const float* bm2 = (const float*)d_in[27];
  const float* Wm3 = (const float*)d_in[28];
  const float* bm3 = (const float*)d_in[29];
  float* out = (float*)d_out;

  // workspace carve
  char* ws = (char*)d_ws;
  size_t off = 0;
  auto alloc = [&](size_t bytes) -> void* {
    void* p = ws + off;
    off = (off + bytes + 511) & ~(size_t)511;
    return p;
  };
  const size_t nf = (size_t)N * 128 * sizeof(float);
  float* P0 = (float*)alloc(nf);   // S0 / agg
  float* P1 = (float*)alloc(nf);   // S1 / g2
  float* P2 = (float*)alloc(nf);   // S2 / g3
  float* P3 = (float*)alloc(nf);   // S3
  float* P4 = (float*)alloc(nf);   // g1
  float* dinv = (float*)alloc((size_t)5 * tn * sizeof(float));
  float* trel = (float*)alloc((size_t)N * sizeof(float));
  float* trot = (float*)alloc((size_t)N * sizeof(float));
  float* sco  = (float*)alloc((size_t)N * sizeof(float));
  int* rowptr = (int*)alloc((size_t)(tn + 1) * sizeof(int));
  int* cnt    = (int*)alloc((size_t)tn * sizeof(int));
  int* csr    = (int*)alloc((size_t)tE * sizeof(int));
  int* csrSrc = (int*)alloc((size_t)tE * sizeof(int));
  float4* csrW = (float4*)alloc((size_t)tE * sizeof(float4));
  float* csrWO = (float*)alloc((size_t)tE * sizeof(float));
  int* bsum   = (int*)alloc(1024);
  float* rbuf = (float*)alloc((size_t)Bg * 768 * sizeof(float));
  if (off > ws_size) return;

  const int nbN2 = (tn + TPB - 1) / TPB;    // 500
  const int nbE2 = (tE + TPB - 1) / TPB;    // 4000
  const int nbS  = (tn + 511) / 512;        // 250
  const int nbN  = (N + TPB - 1) / TPB;     // 250
  const int nbGather = N / 8;               // 8000
  const int nbGemm = N / 64;                // 1000

  // ---- merged CSR build for both branches ----
  hipMemsetAsync(cnt, 0, (size_t)tn * sizeof(int), stream);
  count2_k<<<nbE2, TPB, 0, stream>>>(ei[0] + E, ei[1] + E, cnt, N, E);
  scan1_k<<<nbS, 512, 0, stream>>>(cnt, rowptr, bsum, tn);
  scan2_k<<<1, TPB, 0, stream>>>(bsum, nbS);
  scan3_k<<<nbS, 512, 0, stream>>>(rowptr, bsum, tn, tE);
  hipMemsetAsync(cnt, 0, (size_t)tn * sizeof(int), stream);
  fill2_k<<<nbE2, TPB, 0, stream>>>(ei[0] + E, ei[1] + E, rowptr, cnt, csr, N, E);
  sortadj_k<<<nbN2, TPB, 0, stream>>>(rowptr, csr, tn);
  deg2_k<<<nbN2, TPB, 0, stream>>>(rowptr, csr, eat[0], eat[1], dinv, N, E);
  eresolve2_k<<<nbE2, TPB, 0, stream>>>(csr, ei[0], ei[1], eat[0], eat[1],
                                        dinv, N, E, csrSrc, csrW, csrWO);

  for (int br = 0; br < 2; ++br) {
    const int* rowptr_b = rowptr + (size_t)br * N;
    const float* dinvp = dinv + (size_t)br * N;
    const float* dinvO = dinv + (size_t)4 * tn + (size_t)br * N;

    // conv1
    gather4_k<<<nbGather, 256, 0, stream>>>(
        (const float4*)x[br], rowptr_b, csrSrc, csrW, dinvp, tn,
        (float4*)P0, (float4*)P1, (float4*)P2, (float4*)P3);
    gemm4_k<<<nbGemm, 256, 0, stream>>>(P0, P1, P2, P3,
                                        W1[0], W1[1], W1[2], W1[3],
                                        b1[0], b1[1], b1[2], b1[3], P4, N);

    // conv2
    gather1_k<<<nbGather, 256, 0, stream>>>(
        (const float4*)P4, rowptr_b, csrSrc, csrWO, dinvO, N, (float4*)P0);
    gemm_epi<true><<<nbGemm, 256, 0, stream>>>(P0, W2, b2, P1, N);

    // conv3
    gather1_k<<<nbGather, 256, 0, stream>>>(
        (const float4*)P1, rowptr_b, csrSrc, csrWO, dinvO, N, (float4*)P0);
    gemm_epi<false><<<nbGemm, 256, 0, stream>>>(P0, W3, b3, P2, N);

    // score + top-k pool (g1=P4, g2=P1, g3=P2)
    score_a<<<(N + 3) / 4, 256, 0, stream>>>(P4, P1, P2, Wsrel, Wsroot, trel, trot, N);
    score_b<<<nbN, TPB, 0, stream>>>(rowptr_b, csrSrc, trel, trot, bsrel, sco, N);
    topk_pool<<<Bg, 512, 0, stream>>>(sco, P4, P1, P2, rbuf, br, npg, kq);
  }

  mlp_k<<<Bg, 64, 0, stream>>>(rbuf, Wm1, bm1, Wm2, bm2, Wm3, bm3, out);
}